// Round 8
// baseline (237.324 us; speedup 1.0000x reference)
//
#include <hip/hip_runtime.h>
#include <hip/hip_fp16.h>
#include <stdint.h>

// ---------------------------------------------------------------------------
// ClusterPolicyNetwork: MHA (f16 scores, fp32 softmax/ctx) + pairwise MLP
// (f16 MFMA, kout-split wave pairs). d_out: matching[1M]|coord[32]|attn_w[1M]
// Launches: proj_fused -> scores(f16) -> attn_pre -> ctx -> attn_post -> score
// ---------------------------------------------------------------------------

typedef __attribute__((ext_vector_type(4))) float floatx4;
typedef __attribute__((ext_vector_type(8))) _Float16 half8;

// workspace offsets (bytes)
#define OFF_QKV  0x000000u    // 1024*384*4
#define OFF_CTX  0x180000u    // 1024*128*4
#define OFF_T1H  0x280000u    // 1024*256*2 (f16, includes +b1)
#define OFF_N1H  0x300000u    // 1024*256*2 (f16)
#define OFF_W2F  0x380000u    // 65536 (f16 MFMA frags)
#define OFF_GS   0x398000u    // 128*4
#define OFF_SM   0x3A0000u    // 4*1024*4 softmax row max
#define OFF_SL   0x3A8000u    // 4*1024*4 softmax row sum
#define OFF_SC   0x400000u    // 4*1024*1024*2 = 8 MB f16 raw scores

__device__ __forceinline__ unsigned pkadd(unsigned a, unsigned b) {
    unsigned r; asm("v_pk_add_f16 %0, %1, %2" : "=v"(r) : "v"(a), "v"(b)); return r;
}
__device__ __forceinline__ unsigned pkmax(unsigned a, unsigned b) {
    unsigned r; asm("v_pk_max_f16 %0, %1, %2" : "=v"(r) : "v"(a), "v"(b)); return r;
}
__device__ __forceinline__ unsigned pk2h(float a, float b) {
    return (unsigned)__half_as_ushort(__float2half(a)) |
           ((unsigned)__half_as_ushort(__float2half(b)) << 16);
}
__device__ __forceinline__ float h2f(unsigned short u) {
    return __half2float(__ushort_as_half(u));
}

// ---------------------------------------------------------------------------
// fp32 GEMM tile body: C = scale*(A @ B^T) [+ bias], 64x64 tile, 256 thr.
// ---------------------------------------------------------------------------
template<bool BIAS, bool F16OUT>
__device__ __forceinline__ void gemm_dev(
    const float* __restrict__ A, int lda,
    const float* __restrict__ B, int ldb,
    const float* __restrict__ bias,
    void* __restrict__ Cv, int ldc, int K, float scale,
    int m0, int n0, float (*As)[64], float (*Bs)[64])
{
    const int tid = threadIdx.x;
    const int tx = tid & 15, ty = tid >> 4;
    const int lr = tid >> 2;
    const int lk = (tid & 3) * 4;
    float c[4][4] = {};

    for (int k0 = 0; k0 < K; k0 += 16) {
        float4 a  = *(const float4*)&A[(long)(m0 + lr) * lda + k0 + lk];
        float4 bb = *(const float4*)&B[(long)(n0 + lr) * ldb + k0 + lk];
        __syncthreads();
        As[lk + 0][lr] = a.x;  As[lk + 1][lr] = a.y;  As[lk + 2][lr] = a.z;  As[lk + 3][lr] = a.w;
        Bs[lk + 0][lr] = bb.x; Bs[lk + 1][lr] = bb.y; Bs[lk + 2][lr] = bb.z; Bs[lk + 3][lr] = bb.w;
        __syncthreads();
#pragma unroll
        for (int k = 0; k < 16; k++) {
            float4 av = *(const float4*)&As[k][ty * 4];
            float4 bv = *(const float4*)&Bs[k][tx * 4];
            c[0][0] += av.x * bv.x; c[0][1] += av.x * bv.y; c[0][2] += av.x * bv.z; c[0][3] += av.x * bv.w;
            c[1][0] += av.y * bv.x; c[1][1] += av.y * bv.y; c[1][2] += av.y * bv.z; c[1][3] += av.y * bv.w;
            c[2][0] += av.z * bv.x; c[2][1] += av.z * bv.y; c[2][2] += av.z * bv.z; c[2][3] += av.z * bv.w;
            c[3][0] += av.w * bv.x; c[3][1] += av.w * bv.y; c[3][2] += av.w * bv.z; c[3][3] += av.w * bv.w;
        }
    }

    float bsv[4] = {0.f, 0.f, 0.f, 0.f};
    if (BIAS) {
        float4 t = *(const float4*)&bias[n0 + tx * 4];
        bsv[0] = t.x; bsv[1] = t.y; bsv[2] = t.z; bsv[3] = t.w;
    }
#pragma unroll
    for (int i = 0; i < 4; i++) {
        float v0 = c[i][0] * scale + bsv[0];
        float v1 = c[i][1] * scale + bsv[1];
        float v2 = c[i][2] * scale + bsv[2];
        float v3 = c[i][3] * scale + bsv[3];
        long m = m0 + ty * 4 + i;
        if (F16OUT) {
            unsigned short* Cp = (unsigned short*)Cv;
            ushort4 o;
            o.x = __half_as_ushort(__float2half(v0));
            o.y = __half_as_ushort(__float2half(v1));
            o.z = __half_as_ushort(__float2half(v2));
            o.w = __half_as_ushort(__float2half(v3));
            *(ushort4*)&Cp[m * ldc + n0 + tx * 4] = o;
        } else {
            float* Cp = (float*)Cv;
            *(float4*)&Cp[m * ldc + n0 + tx * 4] = make_float4(v0, v1, v2, v3);
        }
    }
}

// ---------------------------------------------------------------------------
// Launch 1: qkv gemm (96) + t1h gemm (64) + w2prep (16) + gs zero (1)
// ---------------------------------------------------------------------------
__launch_bounds__(256)
__global__ void proj_fused(const float* __restrict__ node, const float* __restrict__ ipw,
                           const float* __restrict__ ipb,
                           const float* __restrict__ task, const float* __restrict__ W1,
                           const float* __restrict__ b1, const float* __restrict__ W2,
                           float* __restrict__ qkv, unsigned short* __restrict__ t1h,
                           unsigned short* __restrict__ w2f, float* __restrict__ gs)
{
    __shared__ float As[16][64], Bs[16][64];
    const int bid = blockIdx.x;
    if (bid < 96) {
        gemm_dev<true, false>(node, 128, ipw, 128, ipb, qkv, 384, 128, 1.0f,
                              (bid & 15) * 64, (bid >> 4) * 64, As, Bs);
    } else if (bid < 160) {
        const int b = bid - 96;
        gemm_dev<true, true>(task, 128, W1, 256, b1, t1h, 256, 128, 1.0f,
                             (b & 15) * 64, (b >> 4) * 64, As, Bs);
    } else if (bid < 176) {
        // W2 -> f16 MFMA fragment layout:
        // frag[((cc*8+ot)*64+lane)*8+j] = f16(W2[ot*16+(lane&15)][cc*32+(lane>>4)*8+j])
        const int gtid = (bid - 160) * 256 + threadIdx.x;  // 0..4095
        const int lane = gtid & 63, frag = gtid >> 6;
        const int cc = frag >> 3, ot = frag & 7;
        const float* src = &W2[(ot * 16 + (lane & 15)) * 256 + cc * 32 + (lane >> 4) * 8];
        uint4 o;
        o.x = pk2h(src[0], src[1]);
        o.y = pk2h(src[2], src[3]);
        o.z = pk2h(src[4], src[5]);
        o.w = pk2h(src[6], src[7]);
        ((uint4*)w2f)[gtid] = o;
    } else {
        if (threadIdx.x < 128) gs[threadIdx.x] = 0.f;
    }
}

// ---------------------------------------------------------------------------
// Launch 2: scores[h] = Qh @ Kh^T / sqrt(32) -> f16, grid (16,16,4)
// ---------------------------------------------------------------------------
__launch_bounds__(256)
__global__ void scores_kernel(const float* __restrict__ qkv, unsigned short* __restrict__ sc16)
{
    __shared__ float As[16][64], Bs[16][64];
    const int h = blockIdx.z;
    gemm_dev<false, true>(qkv + h * 32, 384, qkv + 128 + h * 32, 384, nullptr,
                          sc16 + ((size_t)h << 20), 1024, 32, 0.17677669529663687f,
                          blockIdx.x * 64, blockIdx.y * 64, As, Bs);
}

// ---------------------------------------------------------------------------
// Launch 3: attn_pre — 1024 blocks, one q-row each: softmax stats (-> global
// sm/sl), head-averaged attn_w output, and zero this q-row of ctx.
// ---------------------------------------------------------------------------
__launch_bounds__(256)
__global__ void attn_pre(const unsigned short* __restrict__ sc16,
                         float* __restrict__ sm, float* __restrict__ sl,
                         float* __restrict__ attn_out, float* __restrict__ ctx)
{
    __shared__ float Ps[4][1024];   // 16 KB
    __shared__ float stm[4], stl[4];
    const int t = threadIdx.x;
    const int q = blockIdx.x;

    // stage + dequant (coalesced 8B/lane)
#pragma unroll
    for (int h = 0; h < 4; h++) {
        ushort4 u = *(const ushort4*)&sc16[((size_t)h << 20) + (size_t)q * 1024 + t * 4];
        *(float4*)&Ps[h][t * 4] = make_float4(h2f(u.x), h2f(u.y), h2f(u.z), h2f(u.w));
    }
    // zero ctx row q while loads are in flight
    if (t < 128) ctx[(size_t)q * 128 + t] = 0.f;
    __syncthreads();

    // wave wv handles row h = wv
    {
        const int h = t >> 6, ln = t & 63;
        float4 v[4];
        float mx = -1e30f;
#pragma unroll
        for (int i = 0; i < 4; i++) {
            v[i] = *(const float4*)&Ps[h][ln * 4 + i * 256];
            mx = fmaxf(mx, fmaxf(fmaxf(v[i].x, v[i].y), fmaxf(v[i].z, v[i].w)));
        }
#pragma unroll
        for (int m = 1; m < 64; m <<= 1) mx = fmaxf(mx, __shfl_xor(mx, m));
        float s = 0.f;
#pragma unroll
        for (int i = 0; i < 4; i++)
            s += __expf(v[i].x - mx) + __expf(v[i].y - mx) +
                 __expf(v[i].z - mx) + __expf(v[i].w - mx);
#pragma unroll
        for (int m = 1; m < 64; m <<= 1) s += __shfl_xor(s, m);
        if (ln == 0) {
            stm[h] = mx; stl[h] = s;
            sm[h * 1024 + q] = mx; sl[h * 1024 + q] = s;
        }
    }
    __syncthreads();

    float a0 = 0.f, a1 = 0.f, a2 = 0.f, a3 = 0.f;
#pragma unroll
    for (int h = 0; h < 4; h++) {
        const float m = stm[h], il = 1.0f / stl[h];
        float4 f = *(const float4*)&Ps[h][t * 4];
        a0 += __expf(f.x - m) * il;
        a1 += __expf(f.y - m) * il;
        a2 += __expf(f.z - m) * il;
        a3 += __expf(f.w - m) * il;
    }
    *(float4*)&attn_out[(size_t)q * 1024 + t * 4] =
        make_float4(0.25f * a0, 0.25f * a1, 0.25f * a2, 0.25f * a3);
}

// ---------------------------------------------------------------------------
// Launch 4: ctx = softmax(sc16) @ V, split-k over 8 chunks, fp32 atomicAdd.
// exp applied on the A-tile load (no probs materialization).
// ---------------------------------------------------------------------------
__launch_bounds__(256)
__global__ void ctx_kernel(const unsigned short* __restrict__ sc16,
                           const float* __restrict__ sm, const float* __restrict__ sl,
                           const float* __restrict__ qkv, float* __restrict__ ctx)
{
    const int h = blockIdx.z;
    const int q0 = blockIdx.x * 64;
    const int kbase = blockIdx.y * 128;
    __shared__ float As[32][64];
    __shared__ float Vs[32][32];
    const int tid = threadIdx.x;
    const int tx = tid & 15, ty = tid >> 4;
    const int sq = tid >> 3;
    const int sk4 = (tid & 7) * 4;
    float acc[4][2] = {};

    for (int k0 = kbase; k0 < kbase + 128; k0 += 32) {
        __syncthreads();
#pragma unroll
        for (int half = 0; half < 2; half++) {
            int q = sq + half * 32;
            float m = sm[h * 1024 + q0 + q];
            float il = 1.0f / sl[h * 1024 + q0 + q];
            ushort4 u = *(const ushort4*)&sc16[((size_t)h << 20) + (size_t)(q0 + q) * 1024 + k0 + sk4];
            As[sk4 + 0][q] = __expf(h2f(u.x) - m) * il;
            As[sk4 + 1][q] = __expf(h2f(u.y) - m) * il;
            As[sk4 + 2][q] = __expf(h2f(u.z) - m) * il;
            As[sk4 + 3][q] = __expf(h2f(u.w) - m) * il;
        }
        *(float4*)&Vs[sq][sk4] = *(const float4*)&qkv[(long)(k0 + sq) * 384 + 256 + h * 32 + sk4];
        __syncthreads();
#pragma unroll
        for (int k = 0; k < 32; k++) {
            float4 a = *(const float4*)&As[k][tx * 4];
            float b0 = Vs[k][ty * 2], b1 = Vs[k][ty * 2 + 1];
            acc[0][0] += a.x * b0; acc[0][1] += a.x * b1;
            acc[1][0] += a.y * b0; acc[1][1] += a.y * b1;
            acc[2][0] += a.z * b0; acc[2][1] += a.z * b1;
            acc[3][0] += a.w * b0; acc[3][1] += a.w * b1;
        }
    }
#pragma unroll
    for (int i = 0; i < 4; i++) {
        atomicAdd(&ctx[(long)(q0 + tx * 4 + i) * 128 + h * 32 + ty * 2 + 0], acc[i][0]);
        atomicAdd(&ctx[(long)(q0 + tx * 4 + i) * 128 + h * 32 + ty * 2 + 1], acc[i][1]);
    }
}

// ---------------------------------------------------------------------------
// Launch 5: attn_post — 256 blocks x 4 q-rows: attended = ctx@outw^T+outb,
// gs column sums, n1h = attended @ W1[:,128:]^T (f16).
// ---------------------------------------------------------------------------
__launch_bounds__(256)
__global__ void attn_post(const float* __restrict__ ctx, const float* __restrict__ outw,
                          const float* __restrict__ outb, const float* __restrict__ W1,
                          unsigned short* __restrict__ n1h, float* __restrict__ gs)
{
    __shared__ float ctxs[4][128];
    __shared__ float attr[4][128];
    const int t = threadIdx.x;
    const int q0 = blockIdx.x * 4;

    {
        float2 v = *(const float2*)&ctx[(size_t)q0 * 128 + t * 2];
        ((float2*)&ctxs[0][0])[t] = v;
    }
    __syncthreads();

    {
        const int j = t & 127, qp = t >> 7;
        float a0 = outb[j], a1 = a0;
        const float* wr = &outw[j * 128];
        for (int d = 0; d < 128; d += 4) {
            float4 w  = *(const float4*)&wr[d];
            float4 c0 = *(const float4*)&ctxs[qp * 2 + 0][d];
            float4 c1 = *(const float4*)&ctxs[qp * 2 + 1][d];
            a0 += w.x * c0.x + w.y * c0.y + w.z * c0.z + w.w * c0.w;
            a1 += w.x * c1.x + w.y * c1.y + w.z * c1.z + w.w * c1.w;
        }
        attr[qp * 2 + 0][j] = a0;
        attr[qp * 2 + 1][j] = a1;
    }
    __syncthreads();
    if (t < 128) atomicAdd(&gs[t], attr[0][t] + attr[1][t] + attr[2][t] + attr[3][t]);

    {
        const int c = t;
        const float* wr = &W1[c * 256 + 128];
        float n[4] = {};
        for (int d = 0; d < 128; d += 4) {
            float4 w = *(const float4*)&wr[d];
#pragma unroll
            for (int q = 0; q < 4; q++) {
                float4 a = *(const float4*)&attr[q][d];
                n[q] += w.x * a.x + w.y * a.y + w.z * a.z + w.w * a.w;
            }
        }
#pragma unroll
        for (int q = 0; q < 4; q++)
            n1h[(size_t)(q0 + q) * 256 + c] = __half_as_ushort(__float2half(n[q]));
    }
}

// ---------------------------------------------------------------------------
// Launch 6: matching scores, kout-split wave pairs. Grid (32,33); y==32
// hosts coord head. Wave w: pair=w>>1 (n-set), half=w&1 (kout half).
// Per wave-group: 8 t's, 4 ot slices; each W2 B-frag LDS read feeds 8 MFMAs
// (2x fewer LDS reads per FLOP than the 4-t/8-ot layout). Halves exchange
// W3-partials through a 2 KB LDS buffer.
// ---------------------------------------------------------------------------
__launch_bounds__(256, 2)
__global__ void score_kernel(const unsigned short* __restrict__ t1h,
                             const unsigned short* __restrict__ n1h,
                             const unsigned short* __restrict__ w2f,
                             const float* __restrict__ b2, const float* __restrict__ W3,
                             const float* __restrict__ b3, float* __restrict__ out,
                             const float* __restrict__ gs,
                             const float* __restrict__ Wc1, const float* __restrict__ bc1,
                             const float* __restrict__ Wc2, const float* __restrict__ bc2,
                             float* __restrict__ outc)
{
    __shared__ unsigned short w2s[32768];   // 64 KB
    __shared__ float pp[4][8][16];          // 2 KB: per-wave W3 partials
    __shared__ float b2s[128], w3s[128];
    const int tid = threadIdx.x;

    if (blockIdx.y == 32) {
        if (blockIdx.x != 0) return;
        float* g  = (float*)w2s;
        float* hh = g + 128;
        if (tid < 128) g[tid] = gs[tid] * (1.0f / 1024.0f);
        __syncthreads();
        {
            float a = bc1[tid];
            const float* wr = &Wc1[tid * 128];
            for (int d = 0; d < 128; d += 4) {
                float4 w = *(const float4*)&wr[d];
                a += w.x * g[d] + w.y * g[d + 1] + w.z * g[d + 2] + w.w * g[d + 3];
            }
            hh[tid] = fmaxf(a, 0.f);
        }
        __syncthreads();
        if (tid < 32) {
            float a = bc2[tid];
            const float* wr = &Wc2[tid * 256];
            for (int c = 0; c < 256; c += 4) {
                float4 w = *(const float4*)&wr[c];
                a += w.x * hh[c] + w.y * hh[c + 1] + w.z * hh[c + 2] + w.w * hh[c + 3];
            }
            outc[tid] = a;
        }
        return;
    }

    const int lane = tid & 63;
    const int wv = tid >> 6;
    const int pair = wv >> 1;       // n-set within block
    const int half = wv & 1;        // kout half (ot = half*4 + oi)
    const int col = lane & 15;
    const int quad = lane >> 4;
    const int nb = blockIdx.x * 32 + pair * 16;
    const int tb = blockIdx.y * 32;

    // stage W2 fragments + tables -> LDS
    {
        const uint4* src = (const uint4*)w2f;
        uint4* dst = (uint4*)w2s;
#pragma unroll
        for (int i = 0; i < 16; i++) dst[tid + i * 256] = src[tid + i * 256];
        if (tid < 128) { b2s[tid] = b2[tid]; w3s[tid] = W3[tid]; }
    }

    // n1 slice for this lane (16 n per pair), all K=256: 32 VGPRs
    const int myn = nb + col;
    uint4 n1p[8];
#pragma unroll
    for (int cc = 0; cc < 8; cc++)
        n1p[cc] = *(const uint4*)(n1h + (size_t)myn * 256 + cc * 32 + quad * 8);

    const float b3s = b3[0];
    __syncthreads();

    for (int tg = 0; tg < 4; tg++) {
        floatx4 acc[8][4] = {};   // [tt][oi] 128 regs

#pragma unroll
        for (int cc = 0; cc < 8; cc++) {
            // JIT t-loads (L1-hot broadcast)
            uint4 tp[8];
#pragma unroll
            for (int tt = 0; tt < 8; tt++)
                tp[tt] = *(const uint4*)(t1h + (size_t)(tb + tg * 8 + tt) * 256 + cc * 32 + quad * 8);

            const unsigned* npu = (const unsigned*)&n1p[cc];
            union { unsigned u[4]; half8 h; } af[8];
#pragma unroll
            for (int tt = 0; tt < 8; tt++) {
                const unsigned* tpu = (const unsigned*)&tp[tt];
#pragma unroll
                for (int p = 0; p < 4; p++)
                    af[tt].u[p] = pkmax(pkadd(tpu[p], npu[p]), 0u);
            }
#pragma unroll
            for (int oi = 0; oi < 4; oi++) {
                union { uint4 u; half8 h; } bf;
                bf.u = *(const uint4*)&w2s[((cc * 8 + half * 4 + oi) * 64 + lane) * 8];
#pragma unroll
                for (int tt = 0; tt < 8; tt++)   // A = W2-frag, B = h1-frag
                    acc[tt][oi] = __builtin_amdgcn_mfma_f32_16x16x32_f16(bf.h, af[tt].h, acc[tt][oi], 0, 0, 0);
            }
        }

        // epilogue: this half's partial W3-sum per (tt, n)
        float p[8] = {};
#pragma unroll
        for (int oi = 0; oi < 4; oi++) {
            float4 bq = *(const float4*)&b2s[(half * 4 + oi) * 16 + quad * 4];
            float4 wq = *(const float4*)&w3s[(half * 4 + oi) * 16 + quad * 4];
#pragma unroll
            for (int tt = 0; tt < 8; tt++) {
                floatx4 a = acc[tt][oi];
                p[tt] += fmaxf(a[0] + bq.x, 0.f) * wq.x + fmaxf(a[1] + bq.y, 0.f) * wq.y
                       + fmaxf(a[2] + bq.z, 0.f) * wq.z + fmaxf(a[3] + bq.w, 0.f) * wq.w;
            }
        }
#pragma unroll
        for (int tt = 0; tt < 8; tt++) {
            p[tt] += __shfl_xor(p[tt], 16);
            p[tt] += __shfl_xor(p[tt], 32);
        }
        // exchange halves via LDS
        __syncthreads();   // previous tg's pp reads complete
        {
            const int tt0 = quad * 2;
            pp[wv][tt0 + 0][col] = p[tt0 + 0];
            pp[wv][tt0 + 1][col] = p[tt0 + 1];
        }
        __syncthreads();
        if (half == 0) {
            const int tt0 = quad * 2;
#pragma unroll
            for (int s = 0; s < 2; s++) {
                const int tt = tt0 + s;
                float sum = p[tt] + pp[wv + 1][tt][col];
                out[(size_t)(tb + tg * 8 + tt) * 1024 + nb + col] =
                    1.0f / (1.0f + __expf(-(sum + b3s)));
            }
        }
    }
}

// ---------------------------------------------------------------------------
extern "C" void kernel_launch(void* const* d_in, const int* in_sizes, int n_in,
                              void* d_out, int out_size, void* d_ws, size_t ws_size,
                              hipStream_t stream)
{
    const float* node = (const float*)d_in[0];
    const float* task = (const float*)d_in[1];
    const float* ipw  = (const float*)d_in[2];
    const float* ipb  = (const float*)d_in[3];
    const float* outw = (const float*)d_in[4];
    const float* outb = (const float*)d_in[5];
    const float* W1   = (const float*)d_in[6];
    const float* b1   = (const float*)d_in[7];
    const float* W2   = (const float*)d_in[8];
    const float* b2   = (const float*)d_in[9];
    const float* W3   = (const float*)d_in[10];
    const float* b3   = (const float*)d_in[11];
    const float* Wc1  = (const float*)d_in[12];
    const float* bc1  = (const float*)d_in[13];
    const float* Wc2  = (const float*)d_in[14];
    const float* bc2  = (const float*)d_in[15];

    char* ws = (char*)d_ws;
    float* qkv = (float*)(ws + OFF_QKV);
    float* ctx = (float*)(ws + OFF_CTX);
    unsigned short* t1h = (unsigned short*)(ws + OFF_T1H);
    unsigned short* n1h = (unsigned short*)(ws + OFF_N1H);
    unsigned short* w2f = (unsigned short*)(ws + OFF_W2F);
    float* gs = (float*)(ws + OFF_GS);
    float* sm = (float*)(ws + OFF_SM);
    float* sl = (float*)(ws + OFF_SL);
    unsigned short* sc16 = (unsigned short*)(ws + OFF_SC);

    float* out_match = (float*)d_out;
    float* out_coord = out_match + 1048576;
    float* out_attn  = out_coord + 32;

    // 1. qkv + t1h + w2prep + gs zero
    proj_fused<<<dim3(177, 1, 1), 256, 0, stream>>>(
        node, ipw, ipb, task, W1, b1, W2, qkv, t1h, w2f, gs);
    // 2. raw scores (f16)
    scores_kernel<<<dim3(16, 16, 4), 256, 0, stream>>>(qkv, sc16);
    // 3. softmax stats + attn_w + ctx zero
    attn_pre<<<dim3(1024, 1, 1), 256, 0, stream>>>(sc16, sm, sl, out_attn, ctx);
    // 4. ctx = softmax @ V (split-k)
    ctx_kernel<<<dim3(16, 8, 4), 256, 0, stream>>>(sc16, sm, sl, qkv, ctx);
    // 5. out-proj + gs + n1h
    attn_post<<<dim3(256, 1, 1), 256, 0, stream>>>(ctx, outw, outb, W1, n1h, gs);
    // 6. matching scores + coord head
    score_kernel<<<dim3(32, 33, 1), 256, 0, stream>>>(
        t1h, n1h, w2f, b2, W3, b3, out_match,
        gs, Wc1, bc1, Wc2, bc2, out_coord);
}

// Round 10
// 195.900 us; speedup vs baseline: 1.2115x; 1.2115x over previous
//
#include <hip/hip_runtime.h>
#include <hip/hip_fp16.h>
#include <stdint.h>

// ---------------------------------------------------------------------------
// ClusterPolicyNetwork: MHA (f16 scores, fp32 softmax/ctx) + pairwise MLP
// (f16 MFMA). Fully deterministic (no fp32 atomics on the value path).
// d_out: matching[1M]|coord[32]|attn_w[1M]
// Launches: proj_fused -> scores(f16) -> attn_pre -> ctx(partials)
//           -> attn_post(reduce+outproj+n1h) -> score(+coord)
// ---------------------------------------------------------------------------

typedef __attribute__((ext_vector_type(4))) float floatx4;
typedef __attribute__((ext_vector_type(8))) _Float16 half8;

// workspace offsets (bytes)
#define OFF_QKV  0x000000u    // 1024*384*4
#define OFF_T1H  0x280000u    // 1024*256*2 (f16, includes +b1)
#define OFF_N1H  0x300000u    // 1024*256*2 (f16)
#define OFF_W2F  0x380000u    // 65536 (f16 MFMA frags)
#define OFF_GS   0x398000u    // 128*4
#define OFF_SM   0x3A0000u    // 4*1024*4 softmax row max
#define OFF_SL   0x3A8000u    // 4*1024*4 softmax row sum
#define OFF_SC   0x400000u    // 4*1024*1024*2 = 8 MB f16 raw scores
#define OFF_CTP  0xC00000u    // 8*1024*128*4 = 4 MB ctx split-k partials

__device__ __forceinline__ unsigned pkadd(unsigned a, unsigned b) {
    unsigned r; asm("v_pk_add_f16 %0, %1, %2" : "=v"(r) : "v"(a), "v"(b)); return r;
}
__device__ __forceinline__ unsigned pkmax(unsigned a, unsigned b) {
    unsigned r; asm("v_pk_max_f16 %0, %1, %2" : "=v"(r) : "v"(a), "v"(b)); return r;
}
__device__ __forceinline__ unsigned pk2h(float a, float b) {
    return (unsigned)__half_as_ushort(__float2half(a)) |
           ((unsigned)__half_as_ushort(__float2half(b)) << 16);
}
__device__ __forceinline__ float h2f(unsigned short u) {
    return __half2float(__ushort_as_half(u));
}

// ---------------------------------------------------------------------------
// fp32 GEMM tile body: C = scale*(A @ B^T) [+ bias], 64x64 tile, 256 thr.
// ---------------------------------------------------------------------------
template<bool BIAS, bool F16OUT>
__device__ __forceinline__ void gemm_dev(
    const float* __restrict__ A, int lda,
    const float* __restrict__ B, int ldb,
    const float* __restrict__ bias,
    void* __restrict__ Cv, int ldc, int K, float scale,
    int m0, int n0, float (*As)[64], float (*Bs)[64])
{
    const int tid = threadIdx.x;
    const int tx = tid & 15, ty = tid >> 4;
    const int lr = tid >> 2;
    const int lk = (tid & 3) * 4;
    float c[4][4] = {};

    for (int k0 = 0; k0 < K; k0 += 16) {
        float4 a  = *(const float4*)&A[(long)(m0 + lr) * lda + k0 + lk];
        float4 bb = *(const float4*)&B[(long)(n0 + lr) * ldb + k0 + lk];
        __syncthreads();
        As[lk + 0][lr] = a.x;  As[lk + 1][lr] = a.y;  As[lk + 2][lr] = a.z;  As[lk + 3][lr] = a.w;
        Bs[lk + 0][lr] = bb.x; Bs[lk + 1][lr] = bb.y; Bs[lk + 2][lr] = bb.z; Bs[lk + 3][lr] = bb.w;
        __syncthreads();
#pragma unroll
        for (int k = 0; k < 16; k++) {
            float4 av = *(const float4*)&As[k][ty * 4];
            float4 bv = *(const float4*)&Bs[k][tx * 4];
            c[0][0] += av.x * bv.x; c[0][1] += av.x * bv.y; c[0][2] += av.x * bv.z; c[0][3] += av.x * bv.w;
            c[1][0] += av.y * bv.x; c[1][1] += av.y * bv.y; c[1][2] += av.y * bv.z; c[1][3] += av.y * bv.w;
            c[2][0] += av.z * bv.x; c[2][1] += av.z * bv.y; c[2][2] += av.z * bv.z; c[2][3] += av.z * bv.w;
            c[3][0] += av.w * bv.x; c[3][1] += av.w * bv.y; c[3][2] += av.w * bv.z; c[3][3] += av.w * bv.w;
        }
    }

    float bsv[4] = {0.f, 0.f, 0.f, 0.f};
    if (BIAS) {
        float4 t = *(const float4*)&bias[n0 + tx * 4];
        bsv[0] = t.x; bsv[1] = t.y; bsv[2] = t.z; bsv[3] = t.w;
    }
#pragma unroll
    for (int i = 0; i < 4; i++) {
        float v0 = c[i][0] * scale + bsv[0];
        float v1 = c[i][1] * scale + bsv[1];
        float v2 = c[i][2] * scale + bsv[2];
        float v3 = c[i][3] * scale + bsv[3];
        long m = m0 + ty * 4 + i;
        if (F16OUT) {
            unsigned short* Cp = (unsigned short*)Cv;
            ushort4 o;
            o.x = __half_as_ushort(__float2half(v0));
            o.y = __half_as_ushort(__float2half(v1));
            o.z = __half_as_ushort(__float2half(v2));
            o.w = __half_as_ushort(__float2half(v3));
            *(ushort4*)&Cp[m * ldc + n0 + tx * 4] = o;
        } else {
            float* Cp = (float*)Cv;
            *(float4*)&Cp[m * ldc + n0 + tx * 4] = make_float4(v0, v1, v2, v3);
        }
    }
}

// ---------------------------------------------------------------------------
// Launch 1: qkv gemm (96) + t1h gemm (64) + w2prep (16) + gs zero (1)
// ---------------------------------------------------------------------------
__launch_bounds__(256)
__global__ void proj_fused(const float* __restrict__ node, const float* __restrict__ ipw,
                           const float* __restrict__ ipb,
                           const float* __restrict__ task, const float* __restrict__ W1,
                           const float* __restrict__ b1, const float* __restrict__ W2,
                           float* __restrict__ qkv, unsigned short* __restrict__ t1h,
                           unsigned short* __restrict__ w2f, float* __restrict__ gs)
{
    __shared__ float As[16][64], Bs[16][64];
    const int bid = blockIdx.x;
    if (bid < 96) {
        gemm_dev<true, false>(node, 128, ipw, 128, ipb, qkv, 384, 128, 1.0f,
                              (bid & 15) * 64, (bid >> 4) * 64, As, Bs);
    } else if (bid < 160) {
        const int b = bid - 96;
        gemm_dev<true, true>(task, 128, W1, 256, b1, t1h, 256, 128, 1.0f,
                             (b & 15) * 64, (b >> 4) * 64, As, Bs);
    } else if (bid < 176) {
        // W2 -> f16 MFMA fragment layout:
        // frag[((cc*8+ot)*64+lane)*8+j] = f16(W2[ot*16+(lane&15)][cc*32+(lane>>4)*8+j])
        const int gtid = (bid - 160) * 256 + threadIdx.x;  // 0..4095
        const int lane = gtid & 63, frag = gtid >> 6;
        const int cc = frag >> 3, ot = frag & 7;
        const float* src = &W2[(ot * 16 + (lane & 15)) * 256 + cc * 32 + (lane >> 4) * 8];
        uint4 o;
        o.x = pk2h(src[0], src[1]);
        o.y = pk2h(src[2], src[3]);
        o.z = pk2h(src[4], src[5]);
        o.w = pk2h(src[6], src[7]);
        ((uint4*)w2f)[gtid] = o;
    } else {
        if (threadIdx.x < 128) gs[threadIdx.x] = 0.f;
    }
}

// ---------------------------------------------------------------------------
// Launch 2: scores[h] = Qh @ Kh^T / sqrt(32) -> f16, grid (16,16,4)
// ---------------------------------------------------------------------------
__launch_bounds__(256)
__global__ void scores_kernel(const float* __restrict__ qkv, unsigned short* __restrict__ sc16)
{
    __shared__ float As[16][64], Bs[16][64];
    const int h = blockIdx.z;
    gemm_dev<false, true>(qkv + h * 32, 384, qkv + 128 + h * 32, 384, nullptr,
                          sc16 + ((size_t)h << 20), 1024, 32, 0.17677669529663687f,
                          blockIdx.x * 64, blockIdx.y * 64, As, Bs);
}

// ---------------------------------------------------------------------------
// Launch 3: attn_pre — 1024 blocks, one q-row each: softmax stats (-> global
// sm/sl) + head-averaged attn_w output.
// ---------------------------------------------------------------------------
__launch_bounds__(256)
__global__ void attn_pre(const unsigned short* __restrict__ sc16,
                         float* __restrict__ sm, float* __restrict__ sl,
                         float* __restrict__ attn_out)
{
    __shared__ float Ps[4][1024];   // 16 KB
    __shared__ float stm[4], stl[4];
    const int t = threadIdx.x;
    const int q = blockIdx.x;

#pragma unroll
    for (int h = 0; h < 4; h++) {
        ushort4 u = *(const ushort4*)&sc16[((size_t)h << 20) + (size_t)q * 1024 + t * 4];
        *(float4*)&Ps[h][t * 4] = make_float4(h2f(u.x), h2f(u.y), h2f(u.z), h2f(u.w));
    }
    __syncthreads();

    // wave wv handles row h = wv
    {
        const int h = t >> 6, ln = t & 63;
        float4 v[4];
        float mx = -1e30f;
#pragma unroll
        for (int i = 0; i < 4; i++) {
            v[i] = *(const float4*)&Ps[h][ln * 4 + i * 256];
            mx = fmaxf(mx, fmaxf(fmaxf(v[i].x, v[i].y), fmaxf(v[i].z, v[i].w)));
        }
#pragma unroll
        for (int m = 1; m < 64; m <<= 1) mx = fmaxf(mx, __shfl_xor(mx, m));
        float s = 0.f;
#pragma unroll
        for (int i = 0; i < 4; i++)
            s += __expf(v[i].x - mx) + __expf(v[i].y - mx) +
                 __expf(v[i].z - mx) + __expf(v[i].w - mx);
#pragma unroll
        for (int m = 1; m < 64; m <<= 1) s += __shfl_xor(s, m);
        if (ln == 0) {
            stm[h] = mx; stl[h] = s;
            sm[h * 1024 + q] = mx; sl[h * 1024 + q] = s;
        }
    }
    __syncthreads();

    float a0 = 0.f, a1 = 0.f, a2 = 0.f, a3 = 0.f;
#pragma unroll
    for (int h = 0; h < 4; h++) {
        const float m = stm[h], il = 1.0f / stl[h];
        float4 f = *(const float4*)&Ps[h][t * 4];
        a0 += __expf(f.x - m) * il;
        a1 += __expf(f.y - m) * il;
        a2 += __expf(f.z - m) * il;
        a3 += __expf(f.w - m) * il;
    }
    *(float4*)&attn_out[(size_t)q * 1024 + t * 4] =
        make_float4(0.25f * a0, 0.25f * a1, 0.25f * a2, 0.25f * a3);
}

// ---------------------------------------------------------------------------
// Launch 4: ctx partials = softmax(sc16) @ V, split-k over 8 chunks.
// DETERMINISTIC: each ksplit writes its own partial buffer (plain stores).
// grid (16 qtiles, 8 ksplit, 4 heads); heads write disjoint d-ranges.
// ---------------------------------------------------------------------------
__launch_bounds__(256)
__global__ void ctx_kernel(const unsigned short* __restrict__ sc16,
                           const float* __restrict__ sm, const float* __restrict__ sl,
                           const float* __restrict__ qkv, float* __restrict__ ctxp)
{
    const int h = blockIdx.z;
    const int q0 = blockIdx.x * 64;
    const int ks = blockIdx.y;
    const int kbase = ks * 128;
    __shared__ float As[32][64];
    __shared__ float Vs[32][32];
    const int tid = threadIdx.x;
    const int tx = tid & 15, ty = tid >> 4;
    const int sq = tid >> 3;
    const int sk4 = (tid & 7) * 4;
    float acc[4][2] = {};

    for (int k0 = kbase; k0 < kbase + 128; k0 += 32) {
        __syncthreads();
#pragma unroll
        for (int half = 0; half < 2; half++) {
            int q = sq + half * 32;
            float m = sm[h * 1024 + q0 + q];
            float il = 1.0f / sl[h * 1024 + q0 + q];
            ushort4 u = *(const ushort4*)&sc16[((size_t)h << 20) + (size_t)(q0 + q) * 1024 + k0 + sk4];
            As[sk4 + 0][q] = __expf(h2f(u.x) - m) * il;
            As[sk4 + 1][q] = __expf(h2f(u.y) - m) * il;
            As[sk4 + 2][q] = __expf(h2f(u.z) - m) * il;
            As[sk4 + 3][q] = __expf(h2f(u.w) - m) * il;
        }
        *(float4*)&Vs[sq][sk4] = *(const float4*)&qkv[(long)(k0 + sq) * 384 + 256 + h * 32 + sk4];
        __syncthreads();
#pragma unroll
        for (int k = 0; k < 32; k++) {
            float4 a = *(const float4*)&As[k][tx * 4];
            float b0 = Vs[k][ty * 2], b1 = Vs[k][ty * 2 + 1];
            acc[0][0] += a.x * b0; acc[0][1] += a.x * b1;
            acc[1][0] += a.y * b0; acc[1][1] += a.y * b1;
            acc[2][0] += a.z * b0; acc[2][1] += a.z * b1;
            acc[3][0] += a.w * b0; acc[3][1] += a.w * b1;
        }
    }
#pragma unroll
    for (int i = 0; i < 4; i++) {
        *(float2*)&ctxp[((size_t)ks * 1024 + (q0 + tx * 4 + i)) * 128 + h * 32 + ty * 2] =
            make_float2(acc[i][0], acc[i][1]);
    }
}

// ---------------------------------------------------------------------------
// Launch 5: attn_post — 256 blocks x 4 q-rows: reduce 8 ctx partials (fixed
// order), attended = ctx@outw^T+outb, gs col-sums, n1h = attended@W1b^T (f16).
// ---------------------------------------------------------------------------
__launch_bounds__(256)
__global__ void attn_post(const float* __restrict__ ctxp, const float* __restrict__ outw,
                          const float* __restrict__ outb, const float* __restrict__ W1,
                          unsigned short* __restrict__ n1h, float* __restrict__ gs)
{
    __shared__ float ctxs[4][128];
    __shared__ float attr[4][128];
    const int t = threadIdx.x;
    const int q0 = blockIdx.x * 4;

    // deterministic fixed-order reduction of the 8 split-k partials
#pragma unroll
    for (int s = 0; s < 2; s++) {
        const int idx = s * 256 + t;           // 0..511
        const int q = idx >> 7, d = idx & 127;
        float v = 0.f;
#pragma unroll
        for (int ks = 0; ks < 8; ks++)
            v += ctxp[((size_t)ks * 1024 + (q0 + q)) * 128 + d];
        ctxs[q][d] = v;
    }
    __syncthreads();

    {
        const int j = t & 127, qp = t >> 7;
        float a0 = outb[j], a1 = a0;
        const float* wr = &outw[j * 128];
        for (int d = 0; d < 128; d += 4) {
            float4 w  = *(const float4*)&wr[d];
            float4 c0 = *(const float4*)&ctxs[qp * 2 + 0][d];
            float4 c1 = *(const float4*)&ctxs[qp * 2 + 1][d];
            a0 += w.x * c0.x + w.y * c0.y + w.z * c0.z + w.w * c0.w;
            a1 += w.x * c1.x + w.y * c1.y + w.z * c1.z + w.w * c1.w;
        }
        attr[qp * 2 + 0][j] = a0;
        attr[qp * 2 + 1][j] = a1;
    }
    __syncthreads();
    // gs feeds only coord head (own output chunk) — atomic here is fine for
    // matching_scores determinism; values are summed per-block first.
    if (t < 128) atomicAdd(&gs[t], attr[0][t] + attr[1][t] + attr[2][t] + attr[3][t]);

    {
        const int c = t;
        const float* wr = &W1[c * 256 + 128];
        float n[4] = {};
        for (int d = 0; d < 128; d += 4) {
            float4 w = *(const float4*)&wr[d];
#pragma unroll
            for (int q = 0; q < 4; q++) {
                float4 a = *(const float4*)&attr[q][d];
                n[q] += w.x * a.x + w.y * a.y + w.z * a.z + w.w * a.w;
            }
        }
#pragma unroll
        for (int q = 0; q < 4; q++)
            n1h[(size_t)(q0 + q) * 256 + c] = __half_as_ushort(__float2half(n[q]));
    }
}

// ---------------------------------------------------------------------------
// Launch 6: matching scores (grid 16x33; y==32 hosts coord head).
// R7-PROVEN CORE: full-LDS W2, JIT global t-loads, swapped operands,
// zero-init acc, b2/W3 LDS tables in epilogue, no prefetch.
// ---------------------------------------------------------------------------
__launch_bounds__(256, 2)
__global__ void score_kernel(const unsigned short* __restrict__ t1h,
                             const unsigned short* __restrict__ n1h,
                             const unsigned short* __restrict__ w2f,
                             const float* __restrict__ b2, const float* __restrict__ W3,
                             const float* __restrict__ b3, float* __restrict__ out,
                             const float* __restrict__ gs,
                             const float* __restrict__ Wc1, const float* __restrict__ bc1,
                             const float* __restrict__ Wc2, const float* __restrict__ bc2,
                             float* __restrict__ outc)
{
    __shared__ unsigned short w2s[32768];   // 64 KB
    __shared__ float b2s[128], w3s[128];
    const int tid = threadIdx.x;

    if (blockIdx.y == 32) {
        if (blockIdx.x != 0) return;
        float* g  = (float*)w2s;
        float* hh = g + 128;
        if (tid < 128) g[tid] = gs[tid] * (1.0f / 1024.0f);
        __syncthreads();
        {
            float a = bc1[tid];
            const float* wr = &Wc1[tid * 128];
            for (int d = 0; d < 128; d += 4) {
                float4 w = *(const float4*)&wr[d];
                a += w.x * g[d] + w.y * g[d + 1] + w.z * g[d + 2] + w.w * g[d + 3];
            }
            hh[tid] = fmaxf(a, 0.f);
        }
        __syncthreads();
        if (tid < 32) {
            float a = bc2[tid];
            const float* wr = &Wc2[tid * 256];
            for (int c = 0; c < 256; c += 4) {
                float4 w = *(const float4*)&wr[c];
                a += w.x * hh[c] + w.y * hh[c + 1] + w.z * hh[c + 2] + w.w * hh[c + 3];
            }
            outc[tid] = a;
        }
        return;
    }

    const int lane = tid & 63;
    const int wv = tid >> 6;
    const int col = lane & 15;
    const int quad = lane >> 4;
    const int nb = blockIdx.x * 64 + wv * 16;
    const int tb = blockIdx.y * 32;

    // stage W2 fragments + tables -> LDS
    {
        const uint4* src = (const uint4*)w2f;
        uint4* dst = (uint4*)w2s;
#pragma unroll
        for (int i = 0; i < 16; i++) dst[tid + i * 256] = src[tid + i * 256];
        if (tid < 128) { b2s[tid] = b2[tid]; w3s[tid] = W3[tid]; }
    }

    // n1 slice for this lane (16 n-rows per wave), all K=256: 32 VGPRs
    const int myn = nb + col;
    uint4 n1p[8];
#pragma unroll
    for (int cc = 0; cc < 8; cc++)
        n1p[cc] = *(const uint4*)(n1h + (size_t)myn * 256 + cc * 32 + quad * 8);

    const float b3s = b3[0];
    __syncthreads();

    for (int tg = 0; tg < 8; tg++) {
        floatx4 acc[4][8] = {};   // zero init

#pragma unroll
        for (int cc = 0; cc < 8; cc++) {
            // just-in-time t-loads (L1-hot broadcast)
            uint4 tp[4];
#pragma unroll
            for (int tt = 0; tt < 4; tt++)
                tp[tt] = *(const uint4*)(t1h + (size_t)(tb + tg * 4 + tt) * 256 + cc * 32 + quad * 8);

            const unsigned* npu = (const unsigned*)&n1p[cc];
            union { unsigned u[4]; half8 h; } af[4];
#pragma unroll
            for (int tt = 0; tt < 4; tt++) {
                const unsigned* tpu = (const unsigned*)&tp[tt];
#pragma unroll
                for (int p = 0; p < 4; p++)
                    af[tt].u[p] = pkmax(pkadd(tpu[p], npu[p]), 0u);
            }
#pragma unroll
            for (int ot = 0; ot < 8; ot++) {
                union { uint4 u; half8 h; } bf;
                bf.u = *(const uint4*)&w2s[((cc * 8 + ot) * 64 + lane) * 8];
#pragma unroll
                for (int tt = 0; tt < 4; tt++)   // A = W2-frag, B = h1-frag
                    acc[tt][ot] = __builtin_amdgcn_mfma_f32_16x16x32_f16(bf.h, af[tt].h, acc[tt][ot], 0, 0, 0);
            }
        }

        // epilogue: b2 + relu + W3 from LDS tables, in-lane reduce + 2 shuffles
        float part[4] = {0.f, 0.f, 0.f, 0.f};
#pragma unroll
        for (int ot = 0; ot < 8; ot++) {
            float4 bq = *(const float4*)&b2s[ot * 16 + quad * 4];
            float4 wq = *(const float4*)&w3s[ot * 16 + quad * 4];
#pragma unroll
            for (int tt = 0; tt < 4; tt++) {
                floatx4 a = acc[tt][ot];
                part[tt] += fmaxf(a[0] + bq.x, 0.f) * wq.x + fmaxf(a[1] + bq.y, 0.f) * wq.y
                          + fmaxf(a[2] + bq.z, 0.f) * wq.z + fmaxf(a[3] + bq.w, 0.f) * wq.w;
            }
        }
        float outv = 0.f;
#pragma unroll
        for (int tt = 0; tt < 4; tt++) {
            float p = part[tt];
            p += __shfl_xor(p, 16);
            p += __shfl_xor(p, 32);
            if (quad == tt) outv = p;   // quad q keeps t = tg*4 + q
        }
        out[(size_t)(tb + tg * 4 + quad) * 1024 + nb + col] =
            1.0f / (1.0f + __expf(-(outv + b3s)));
    }
}

// ---------------------------------------------------------------------------
extern "C" void kernel_launch(void* const* d_in, const int* in_sizes, int n_in,
                              void* d_out, int out_size, void* d_ws, size_t ws_size,
                              hipStream_t stream)
{
    const float* node = (const float*)d_in[0];
    const float* task = (const float*)d_in[1];
    const float* ipw  = (const float*)d_in[2];
    const float* ipb  = (const float*)d_in[3];
    const float* outw = (const float*)d_in[4];
    const float* outb = (const float*)d_in[5];
    const float* W1   = (const float*)d_in[6];
    const float* b1   = (const float*)d_in[7];
    const float* W2   = (const float*)d_in[8];
    const float* b2   = (const float*)d_in[9];
    const float* W3   = (const float*)d_in[10];
    const float* b3   = (const float*)d_in[11];
    const float* Wc1  = (const float*)d_in[12];
    const float* bc1  = (const float*)d_in[13];
    const float* Wc2  = (const float*)d_in[14];
    const float* bc2  = (const float*)d_in[15];

    char* ws = (char*)d_ws;
    float* qkv = (float*)(ws + OFF_QKV);
    unsigned short* t1h = (unsigned short*)(ws + OFF_T1H);
    unsigned short* n1h = (unsigned short*)(ws + OFF_N1H);
    unsigned short* w2f = (unsigned short*)(ws + OFF_W2F);
    float* gs = (float*)(ws + OFF_GS);
    float* sm = (float*)(ws + OFF_SM);
    float* sl = (float*)(ws + OFF_SL);
    unsigned short* sc16 = (unsigned short*)(ws + OFF_SC);
    float* ctxp = (float*)(ws + OFF_CTP);

    float* out_match = (float*)d_out;
    float* out_coord = out_match + 1048576;
    float* out_attn  = out_coord + 32;

    // 1. qkv + t1h + w2prep + gs zero
    proj_fused<<<dim3(177, 1, 1), 256, 0, stream>>>(
        node, ipw, ipb, task, W1, b1, W2, qkv, t1h, w2f, gs);
    // 2. raw scores (f16)
    scores_kernel<<<dim3(16, 16, 4), 256, 0, stream>>>(qkv, sc16);
    // 3. softmax stats + attn_w
    attn_pre<<<dim3(1024, 1, 1), 256, 0, stream>>>(sc16, sm, sl, out_attn);
    // 4. ctx split-k partials (deterministic, no atomics)
    ctx_kernel<<<dim3(16, 8, 4), 256, 0, stream>>>(sc16, sm, sl, qkv, ctxp);
    // 5. fixed-order reduce + out-proj + gs + n1h
    attn_post<<<dim3(256, 1, 1), 256, 0, stream>>>(ctxp, outw, outb, W1, n1h, gs);
    // 6. matching scores + coord head
    score_kernel<<<dim3(16, 33, 1), 256, 0, stream>>>(
        t1h, n1h, w2f, b2, W3, b3, out_match,
        gs, Wc1, bc1, Wc2, bc2, out_coord);
}